// Round 3
// baseline (81.215 us; speedup 1.0000x reference)
//
#include <hip/hip_runtime.h>

// reference: out[b,l,c,t,f] = prototypes[labels[b,l], c, t, f]
// B=512, L=21, NCHAN=1, T=29, F=129  -> row = NCHAN*T*F = 3741 floats
// total out = 512*21*3741 = 40,223,232 floats (fits in int32)

#define ROW_ELEMS 3741u
#define TOTAL_ELEMS (512u * 21u * 3741u)   // 40,223,232 (divisible by 8)

typedef float f32x4 __attribute__((ext_vector_type(4)));  // native vec for nt-store

__global__ __launch_bounds__(256) void gather_proto_kernel(
    const int* __restrict__ labels,       // (B*L) int32
    const float* __restrict__ protos,     // (25, 3741) float32
    float* __restrict__ out)              // (B*L, 3741) float32
{
    const unsigned nv = TOTAL_ELEMS / 8u;          // 5,027,904 8-elem chunks
    const unsigned stride = gridDim.x * blockDim.x;
    for (unsigned v = blockIdx.x * blockDim.x + threadIdx.x; v < nv; v += stride) {
        const unsigned base = v * 8u;
        const unsigned r0 = base / ROW_ELEMS;      // magic-multiply divide
        const unsigned e0 = base - r0 * ROW_ELEMS;
        if (e0 + 7u < ROW_ELEMS) {
            // whole chunk inside one row: scalar loads (L1/L2 hits),
            // two aligned vec4 non-temporal stores (write stream bypasses L2)
            const float* p = protos + (unsigned)labels[r0] * ROW_ELEMS + e0;
            f32x4 v0, v1;
            v0.x = p[0]; v0.y = p[1]; v0.z = p[2]; v0.w = p[3];
            v1.x = p[4]; v1.y = p[5]; v1.z = p[6]; v1.w = p[7];
            __builtin_nontemporal_store(v0, reinterpret_cast<f32x4*>(out + base));
            __builtin_nontemporal_store(v1, reinterpret_cast<f32x4*>(out + base) + 1);
        } else {
            // chunk straddles a row boundary (~1 per 468 chunks)
#pragma unroll
            for (unsigned k = 0; k < 8u; ++k) {
                const unsigned idx = base + k;
                const unsigned r = idx / ROW_ELEMS;
                const unsigned e = idx - r * ROW_ELEMS;
                out[idx] = protos[(unsigned)labels[r] * ROW_ELEMS + e];
            }
        }
    }
}

extern "C" void kernel_launch(void* const* d_in, const int* in_sizes, int n_in,
                              void* d_out, int out_size, void* d_ws, size_t ws_size,
                              hipStream_t stream) {
    // setup_inputs() order: inputs (unused), labels, prototypes
    const int*   labels = (const int*)d_in[1];
    const float* protos = (const float*)d_in[2];
    float*       out    = (float*)d_out;

    const unsigned nv = TOTAL_ELEMS / 8u;
    unsigned blocks = (nv + 255u) / 256u;
    if (blocks > 2048u) blocks = 2048u;   // grid-stride the rest (G11)
    gather_proto_kernel<<<blocks, 256, 0, stream>>>(labels, protos, out);
}

// Round 4
// 33.714 us; speedup vs baseline: 2.4089x; 2.4089x over previous
//
#include <hip/hip_runtime.h>

// reference: out[b,l,c,t,f] = prototypes[labels[b,l], c, t, f]
// B=512, L=21, NCHAN=1, T=29, F=129  -> row = NCHAN*T*F = 3741 floats
// total out = 512*21*3741 = 40,223,232 floats (fits in int32)
//
// R3 lesson: __builtin_nontemporal_store (nt flag) = 2.7x REGRESSION here —
// streaming writes want the L2 write-combining path, same as rocclr fill.

#define ROW_ELEMS 3741u
#define TOTAL_ELEMS (512u * 21u * 3741u)   // 40,223,232 (divisible by 8)

typedef float f32x4 __attribute__((ext_vector_type(4)));

__global__ __launch_bounds__(256) void gather_proto_kernel(
    const int* __restrict__ labels,       // (B*L) int32
    const float* __restrict__ protos,     // (25, 3741) float32
    float* __restrict__ out)              // (B*L, 3741) float32
{
    const unsigned nv = TOTAL_ELEMS / 8u;          // 5,027,904 8-elem chunks
    const unsigned stride = gridDim.x * blockDim.x;
    for (unsigned v = blockIdx.x * blockDim.x + threadIdx.x; v < nv; v += stride) {
        const unsigned base = v * 8u;
        const unsigned r0 = base / ROW_ELEMS;      // magic-multiply divide
        const unsigned e0 = base - r0 * ROW_ELEMS;
        if (e0 + 7u < ROW_ELEMS) {
            // whole chunk inside one row: scalar loads (L1/L2 hits),
            // two aligned vec4 stores through L2 (write-combining path)
            const float* p = protos + (unsigned)labels[r0] * ROW_ELEMS + e0;
            f32x4 v0, v1;
            v0.x = p[0]; v0.y = p[1]; v0.z = p[2]; v0.w = p[3];
            v1.x = p[4]; v1.y = p[5]; v1.z = p[6]; v1.w = p[7];
            *reinterpret_cast<f32x4*>(out + base)       = v0;
            *(reinterpret_cast<f32x4*>(out + base) + 1) = v1;
        } else {
            // chunk straddles a row boundary (~1 per 468 chunks)
#pragma unroll
            for (unsigned k = 0; k < 8u; ++k) {
                const unsigned idx = base + k;
                const unsigned r = idx / ROW_ELEMS;
                const unsigned e = idx - r * ROW_ELEMS;
                out[idx] = protos[(unsigned)labels[r] * ROW_ELEMS + e];
            }
        }
    }
}

extern "C" void kernel_launch(void* const* d_in, const int* in_sizes, int n_in,
                              void* d_out, int out_size, void* d_ws, size_t ws_size,
                              hipStream_t stream) {
    // setup_inputs() order: inputs (unused), labels, prototypes
    const int*   labels = (const int*)d_in[1];
    const float* protos = (const float*)d_in[2];
    float*       out    = (float*)d_out;

    const unsigned nv = TOTAL_ELEMS / 8u;
    unsigned blocks = (nv + 255u) / 256u;
    if (blocks > 2048u) blocks = 2048u;   // grid-stride the rest (G11)
    gather_proto_kernel<<<blocks, 256, 0, stream>>>(labels, protos, out);
}

// Round 5
// 29.888 us; speedup vs baseline: 2.7173x; 1.1280x over previous
//
#include <hip/hip_runtime.h>

// reference: out[b,l,c,t,f] = prototypes[labels[b,l], c, t, f]
// B=512, L=21, NCHAN=1, T=29, F=129  -> row = NCHAN*T*F = 3741 floats
// total out = 512*21*3741 = 40,223,232 floats (fits in int32)
//
// R3 lesson: nt-stores (L2 bypass) = 2.7x regression — keep the L2
//            write-combining path.
// R4 lesson: 8 floats/lane breaks PER-INSTRUCTION store contiguity
//            (16B written every 32B) = 13% regression. 4 floats/lane
//            (16B/lane, lane-stride 16B) is the coalescing sweet spot.

#define ROW_ELEMS 3741u
#define TOTAL_ELEMS (512u * 21u * 3741u)   // 40,223,232 (divisible by 4)

typedef float f32x4 __attribute__((ext_vector_type(4)));

__device__ __forceinline__ void do_chunk(
    const int* __restrict__ labels,
    const float* __restrict__ protos,
    float* __restrict__ out,
    unsigned v)
{
    const unsigned base = v * 4u;
    const unsigned r0 = base / ROW_ELEMS;      // magic-multiply divide
    const unsigned e0 = base - r0 * ROW_ELEMS;
    if (e0 + 3u < ROW_ELEMS) {
        // whole chunk inside one row: scalar loads (cache hits),
        // one aligned vec4 store -> wave writes contiguous 1KB
        const float* p = protos + (unsigned)labels[r0] * ROW_ELEMS + e0;
        f32x4 val;
        val.x = p[0]; val.y = p[1]; val.z = p[2]; val.w = p[3];
        *reinterpret_cast<f32x4*>(out + base) = val;
    } else {
        // chunk straddles a row boundary (~1/935 chunks)
#pragma unroll
        for (unsigned k = 0; k < 4u; ++k) {
            const unsigned idx = base + k;
            const unsigned r = idx / ROW_ELEMS;
            const unsigned e = idx - r * ROW_ELEMS;
            out[idx] = protos[(unsigned)labels[r] * ROW_ELEMS + e];
        }
    }
}

__global__ __launch_bounds__(256) void gather_proto_kernel(
    const int* __restrict__ labels,       // (B*L) int32
    const float* __restrict__ protos,     // (25, 3741) float32
    float* __restrict__ out)              // (B*L, 3741) float32
{
    const unsigned nv = TOTAL_ELEMS / 4u;          // 10,055,808 vec4 chunks
    const unsigned stride = gridDim.x * blockDim.x; // 524,288
    unsigned v = blockIdx.x * blockDim.x + threadIdx.x;
    // 2x unroll with stride offset: both stores stay fully contiguous
    // per-instruction; two independent load->store chains per iteration.
    for (; v + stride < nv; v += 2u * stride) {
        do_chunk(labels, protos, out, v);
        do_chunk(labels, protos, out, v + stride);
    }
    if (v < nv) do_chunk(labels, protos, out, v);
}

extern "C" void kernel_launch(void* const* d_in, const int* in_sizes, int n_in,
                              void* d_out, int out_size, void* d_ws, size_t ws_size,
                              hipStream_t stream) {
    // setup_inputs() order: inputs (unused), labels, prototypes
    const int*   labels = (const int*)d_in[1];
    const float* protos = (const float*)d_in[2];
    float*       out    = (float*)d_out;

    const unsigned nv = TOTAL_ELEMS / 4u;
    unsigned blocks = (nv + 255u) / 256u;
    if (blocks > 2048u) blocks = 2048u;   // grid-stride the rest (G11)
    gather_proto_kernel<<<blocks, 256, 0, stream>>>(labels, protos, out);
}

// Round 6
// 29.774 us; speedup vs baseline: 2.7278x; 1.0038x over previous
//
#include <hip/hip_runtime.h>

// reference: out[b,l,c,t,f] = prototypes[labels[b,l], c, t, f]
// B=512, L=21, NCHAN=1, T=29, F=129  -> row = NCHAN*T*F = 3741 floats
// total out = 512*21*3741 = 40,223,232 floats (fits in int32)
//
// R3 lesson: nt-stores (L2 bypass) = 2.7x regression — keep the L2
//            write-combining path.
// R4 lesson: 8 floats/lane breaks PER-INSTRUCTION store contiguity
//            (16B written every 32B) = 13% regression. 4 floats/lane is
//            the coalescing sweet spot.
// R5 lesson: 2x unroll = EXACTLY neutral (29.888 vs 29.889 µs) — memory-
//            path floor, insensitive to instruction mix.
// R6 probe:  exact grid, one chunk/thread (last untested axis: launch shape).

#define ROW_ELEMS 3741u
#define TOTAL_ELEMS (512u * 21u * 3741u)   // 40,223,232 (divisible by 4)

typedef float f32x4 __attribute__((ext_vector_type(4)));

__global__ __launch_bounds__(256) void gather_proto_kernel(
    const int* __restrict__ labels,       // (B*L) int32
    const float* __restrict__ protos,     // (25, 3741) float32
    float* __restrict__ out)              // (B*L, 3741) float32
{
    const unsigned nv = TOTAL_ELEMS / 4u;          // 10,055,808 vec4 chunks
    const unsigned v = blockIdx.x * blockDim.x + threadIdx.x;
    if (v >= nv) return;

    const unsigned base = v * 4u;
    const unsigned r0 = base / ROW_ELEMS;      // magic-multiply divide
    const unsigned e0 = base - r0 * ROW_ELEMS;
    if (e0 + 3u < ROW_ELEMS) {
        // whole chunk inside one row: scalar loads (cache hits),
        // one aligned vec4 store -> wave writes contiguous 1KB
        const float* p = protos + (unsigned)labels[r0] * ROW_ELEMS + e0;
        f32x4 val;
        val.x = p[0]; val.y = p[1]; val.z = p[2]; val.w = p[3];
        *reinterpret_cast<f32x4*>(out + base) = val;
    } else {
        // chunk straddles a row boundary (~1/935 chunks)
#pragma unroll
        for (unsigned k = 0; k < 4u; ++k) {
            const unsigned idx = base + k;
            const unsigned r = idx / ROW_ELEMS;
            const unsigned e = idx - r * ROW_ELEMS;
            out[idx] = protos[(unsigned)labels[r] * ROW_ELEMS + e];
        }
    }
}

extern "C" void kernel_launch(void* const* d_in, const int* in_sizes, int n_in,
                              void* d_out, int out_size, void* d_ws, size_t ws_size,
                              hipStream_t stream) {
    // setup_inputs() order: inputs (unused), labels, prototypes
    const int*   labels = (const int*)d_in[1];
    const float* protos = (const float*)d_in[2];
    float*       out    = (float*)d_out;

    const unsigned nv = TOTAL_ELEMS / 4u;          // one chunk per thread
    const unsigned blocks = (nv + 255u) / 256u;    // 39,282 blocks, exact grid
    gather_proto_kernel<<<blocks, 256, 0, stream>>>(labels, protos, out);
}